// Round 1
// baseline (2198.694 us; speedup 1.0000x reference)
//
#include <hip/hip_runtime.h>
#include <hip/hip_bf16.h>
#include <math.h>

// Model constants (from reference): V=32000, D=1024, H=16, L=2, S=2048, W=256
#define SEQ    2048
#define DMODEL 1024
#define NHEAD  16
#define HDIM   64
#define NLAYER 2
#define VOCAB  32000
#define HALFW  128   // W//2

typedef float  f32x4  __attribute__((ext_vector_type(4)));
typedef short  s16x8  __attribute__((ext_vector_type(8)));

// ---------- helpers ----------
__device__ __forceinline__ unsigned bf16_rne(float x) {
    unsigned b = __builtin_bit_cast(unsigned, x);
    return (b + 0x7FFFu + ((b >> 16) & 1u)) >> 16;
}
__device__ __forceinline__ unsigned pack2(float lo, float hi) {
    return bf16_rne(lo) | (bf16_rne(hi) << 16);
}

// ---------- embedding ----------
__global__ __launch_bounds__(256) void embed_kernel(
    const int* __restrict__ ids, const float* __restrict__ emb,
    const float* __restrict__ pos, float* __restrict__ X)
{
    const int s = blockIdx.x;
    const int t = threadIdx.x;
    const int id = ids[s];
    f32x4 e = *(const f32x4*)(emb + (size_t)id * DMODEL + t * 4);
    f32x4 p = *(const f32x4*)(pos + (size_t)s  * DMODEL + t * 4);
    *(f32x4*)(X + (size_t)s * DMODEL + t * 4) = e + p;
}

// ---------- layernorm (one block per row, D=1024) ----------
__global__ __launch_bounds__(256) void ln_kernel(
    const float* __restrict__ X, const float* __restrict__ G,
    const float* __restrict__ Bb, float* __restrict__ Y)
{
    const int row = blockIdx.x;
    const int t = threadIdx.x;
    const float* xp = X + (size_t)row * DMODEL;
    f32x4 v = *(const f32x4*)(xp + t * 4);
    float s1 = v.x + v.y + v.z + v.w;
    float s2 = v.x * v.x + v.y * v.y + v.z * v.z + v.w * v.w;
    #pragma unroll
    for (int off = 32; off; off >>= 1) {
        s1 += __shfl_down(s1, off);
        s2 += __shfl_down(s2, off);
    }
    __shared__ float red[8];
    const int wave = t >> 6, lane = t & 63;
    if (lane == 0) { red[wave] = s1; red[wave + 4] = s2; }
    __syncthreads();
    s1 = red[0] + red[1] + red[2] + red[3];
    s2 = red[4] + red[5] + red[6] + red[7];
    const float mu  = s1 * (1.0f / DMODEL);
    const float var = s2 * (1.0f / DMODEL) - mu * mu;
    const float rs  = rsqrtf(var + 1e-5f);
    f32x4 g = *(const f32x4*)(G + t * 4);
    f32x4 b = *(const f32x4*)(Bb + t * 4);
    f32x4 y;
    y.x = (v.x - mu) * rs * g.x + b.x;
    y.y = (v.y - mu) * rs * g.y + b.y;
    y.z = (v.z - mu) * rs * g.z + b.z;
    y.w = (v.w - mu) * rs * g.w + b.w;
    *(f32x4*)(Y + (size_t)row * DMODEL + t * 4) = y;
}

// ---------- GEMM: C[M,N] = A[M,K] * B (+bias, +gelu, +residual) ----------
// BT=false: B is [K,N] row-major (weights).  BT=true: B is [N,K] row-major (emb for logits).
// f32 inputs, converted to bf16 (RNE) during LDS staging; MFMA 16x16x32 bf16; f32 accum.
// Tiles: BM=BN=128, BK=32. 256 threads = 4 waves in 2x2, each wave does 64x64 (4x4 MFMA tiles).
// LDS rows padded to 40 shorts (80B = 20 banks -> only 2-way conflicts, free per m136).
template<bool BT, int GELU>
__global__ __launch_bounds__(256) void gemm_kernel(
    const float* __restrict__ A, const float* __restrict__ B,
    const float* __restrict__ bias, const float* __restrict__ resid,
    float* __restrict__ C, int M, int N, int K)
{
    __shared__ unsigned As[128 * 20];
    __shared__ unsigned Bs[128 * 20];

    const int t  = threadIdx.x;
    const int m0 = blockIdx.x * 128;
    const int n0 = blockIdx.y * 128;
    const int wave = t >> 6, lane = t & 63;
    const int wm = (wave & 1) * 64, wn = (wave >> 1) * 64;
    const int lrow = lane & 15, quad = lane >> 4;

    // staging assignments
    const int rowA = t >> 1;           // 0..127  (row of A tile / row of BT tile)
    const int colA = (t & 1) * 16;     // 0 or 16 (k offset within tile)
    const int nB   = t & 127;          // column within B tile (non-BT)
    const int kOff = (t >> 7) * 16;    // 0 or 16

    f32x4 acc[4][4] = {};

    for (int k0 = 0; k0 < K; k0 += 32) {
        // ---- global loads to regs ----
        float a_ld[16], b_ld[16];
        {
            const float* ap = A + (size_t)(m0 + rowA) * K + k0 + colA;
            *(f32x4*)(a_ld + 0)  = *(const f32x4*)(ap + 0);
            *(f32x4*)(a_ld + 4)  = *(const f32x4*)(ap + 4);
            *(f32x4*)(a_ld + 8)  = *(const f32x4*)(ap + 8);
            *(f32x4*)(a_ld + 12) = *(const f32x4*)(ap + 12);
        }
        if (BT) {
            const float* bp = B + (size_t)(n0 + rowA) * K + k0 + colA;
            *(f32x4*)(b_ld + 0)  = *(const f32x4*)(bp + 0);
            *(f32x4*)(b_ld + 4)  = *(const f32x4*)(bp + 4);
            *(f32x4*)(b_ld + 8)  = *(const f32x4*)(bp + 8);
            *(f32x4*)(b_ld + 12) = *(const f32x4*)(bp + 12);
        } else {
            const float* bp = B + (size_t)(k0 + kOff) * N + n0 + nB;
            #pragma unroll
            for (int i = 0; i < 16; ++i) b_ld[i] = bp[(size_t)i * N];
        }

        unsigned pa[8], pb[8];
        #pragma unroll
        for (int i = 0; i < 8; ++i) {
            pa[i] = pack2(a_ld[2 * i], a_ld[2 * i + 1]);
            pb[i] = pack2(b_ld[2 * i], b_ld[2 * i + 1]);
        }

        __syncthreads();   // previous iteration's LDS reads complete
        {
            unsigned* aw = &As[rowA * 20 + (colA >> 1)];
            ((uint4*)aw)[0] = make_uint4(pa[0], pa[1], pa[2], pa[3]);
            ((uint4*)aw)[1] = make_uint4(pa[4], pa[5], pa[6], pa[7]);
        }
        if (BT) {
            unsigned* bw = &Bs[rowA * 20 + (colA >> 1)];
            ((uint4*)bw)[0] = make_uint4(pb[0], pb[1], pb[2], pb[3]);
            ((uint4*)bw)[1] = make_uint4(pb[4], pb[5], pb[6], pb[7]);
        } else {
            // transpose into Bs[n][k]
            unsigned* bw = &Bs[nB * 20 + (kOff >> 1)];
            ((uint4*)bw)[0] = make_uint4(pb[0], pb[1], pb[2], pb[3]);
            ((uint4*)bw)[1] = make_uint4(pb[4], pb[5], pb[6], pb[7]);
        }
        __syncthreads();

        // ---- fragments + MFMA ----
        s16x8 af[4], bfr[4];
        #pragma unroll
        for (int i = 0; i < 4; ++i) {
            af[i]  = *(const s16x8*)(&As[(wm + i * 16 + lrow) * 20 + quad * 4]);
            bfr[i] = *(const s16x8*)(&Bs[(wn + i * 16 + lrow) * 20 + quad * 4]);
        }
        #pragma unroll
        for (int i = 0; i < 4; ++i)
            #pragma unroll
            for (int j = 0; j < 4; ++j)
                acc[i][j] = __builtin_amdgcn_mfma_f32_16x16x32_bf16(af[i], bfr[j], acc[i][j], 0, 0, 0);
    }

    // ---- epilogue: C/D layout col=lane&15, row=quad*4+reg (m89-verified) ----
    #pragma unroll
    for (int j = 0; j < 4; ++j) {
        const int col = n0 + wn + j * 16 + lrow;
        const float bv = bias ? bias[col] : 0.0f;
        #pragma unroll
        for (int i = 0; i < 4; ++i) {
            #pragma unroll
            for (int r = 0; r < 4; ++r) {
                const int row = m0 + wm + i * 16 + quad * 4 + r;
                float vv = acc[i][j][r] + bv;
                if (GELU) vv = 0.5f * vv * (1.0f + erff(vv * 0.70710678118f));
                const size_t off = (size_t)row * N + col;
                if (resid) vv += resid[off];
                C[off] = vv;
            }
        }
    }
}

// ---------- local attention (band |q-k| <= 128), online softmax ----------
// Block = 256 threads = 64 queries x 4 chunks of 16 dims. Grid = (S/64, H).
// All 64 lanes of a wave read the SAME key row each iteration -> broadcast loads, L2-resident.
__global__ __launch_bounds__(256) void attn_kernel(
    const float* __restrict__ Q, const float* __restrict__ K,
    const float* __restrict__ V, float* __restrict__ O)
{
    const int t = threadIdx.x;
    const int h = blockIdx.y;
    const int ql = t >> 2;
    const int chunk = t & 3;
    const int q_abs = blockIdx.x * 64 + ql;
    const float scale = 0.125f;  // 1/sqrt(64)

    const float* qp = Q + ((size_t)q_abs * NHEAD + h) * HDIM + chunk * 16;
    float qr[16];
    *(f32x4*)(qr + 0)  = *(const f32x4*)(qp + 0);
    *(f32x4*)(qr + 4)  = *(const f32x4*)(qp + 4);
    *(f32x4*)(qr + 8)  = *(const f32x4*)(qp + 8);
    *(f32x4*)(qr + 12) = *(const f32x4*)(qp + 12);

    float m = -1e30f, l = 0.0f;
    float oa[16] = {};

    const int kbase = blockIdx.x * 64 - HALFW;
    for (int j = 0; j < 64 + 2 * HALFW; ++j) {
        const int key = kbase + j;
        const bool valid = (key >= 0) && (key < SEQ) && (abs(key - q_abs) <= HALFW);
        const int kc = min(max(key, 0), SEQ - 1);

        const float* kp = K + ((size_t)kc * NHEAD + h) * HDIM + chunk * 16;
        float kr[16];
        *(f32x4*)(kr + 0)  = *(const f32x4*)(kp + 0);
        *(f32x4*)(kr + 4)  = *(const f32x4*)(kp + 4);
        *(f32x4*)(kr + 8)  = *(const f32x4*)(kp + 8);
        *(f32x4*)(kr + 12) = *(const f32x4*)(kp + 12);

        float s = 0.0f;
        #pragma unroll
        for (int i = 0; i < 16; ++i) s += qr[i] * kr[i];
        s += __shfl_xor(s, 1);
        s += __shfl_xor(s, 2);
        s = valid ? s * scale : -1e30f;

        const float mn = fmaxf(m, s);
        const float alpha = __expf(m - mn);
        const float p = valid ? __expf(s - mn) : 0.0f;

        const float* vp = V + ((size_t)kc * NHEAD + h) * HDIM + chunk * 16;
        float vr[16];
        *(f32x4*)(vr + 0)  = *(const f32x4*)(vp + 0);
        *(f32x4*)(vr + 4)  = *(const f32x4*)(vp + 4);
        *(f32x4*)(vr + 8)  = *(const f32x4*)(vp + 8);
        *(f32x4*)(vr + 12) = *(const f32x4*)(vp + 12);

        #pragma unroll
        for (int i = 0; i < 16; ++i) oa[i] = oa[i] * alpha + p * vr[i];
        l = l * alpha + p;
        m = mn;
    }

    const float inv = 1.0f / l;
    float* op = O + ((size_t)q_abs * NHEAD + h) * HDIM + chunk * 16;
    f32x4 o0, o1, o2, o3;
    o0.x = oa[0]*inv;  o0.y = oa[1]*inv;  o0.z = oa[2]*inv;  o0.w = oa[3]*inv;
    o1.x = oa[4]*inv;  o1.y = oa[5]*inv;  o1.z = oa[6]*inv;  o1.w = oa[7]*inv;
    o2.x = oa[8]*inv;  o2.y = oa[9]*inv;  o2.z = oa[10]*inv; o2.w = oa[11]*inv;
    o3.x = oa[12]*inv; o3.y = oa[13]*inv; o3.z = oa[14]*inv; o3.w = oa[15]*inv;
    *(f32x4*)(op + 0)  = o0;
    *(f32x4*)(op + 4)  = o1;
    *(f32x4*)(op + 8)  = o2;
    *(f32x4*)(op + 12) = o3;
}

// ---------- launch ----------
extern "C" void kernel_launch(void* const* d_in, const int* in_sizes, int n_in,
                              void* d_out, int out_size, void* d_ws, size_t ws_size,
                              hipStream_t stream)
{
    const int*   ids  = (const int*)d_in[0];
    const float* emb  = (const float*)d_in[1];
    const float* pos  = (const float*)d_in[2];
    const float* wq   = (const float*)d_in[3];
    const float* bq   = (const float*)d_in[4];
    const float* wk   = (const float*)d_in[5];
    const float* bk   = (const float*)d_in[6];
    const float* wv   = (const float*)d_in[7];
    const float* bv   = (const float*)d_in[8];
    const float* wo   = (const float*)d_in[9];
    const float* bo   = (const float*)d_in[10];
    const float* w1   = (const float*)d_in[11];
    const float* b1   = (const float*)d_in[12];
    const float* w2   = (const float*)d_in[13];
    const float* b2   = (const float*)d_in[14];
    const float* ln1g = (const float*)d_in[15];
    const float* ln1b = (const float*)d_in[16];
    const float* ln2g = (const float*)d_in[17];
    const float* ln2b = (const float*)d_in[18];
    const float* outg = (const float*)d_in[19];
    const float* outb = (const float*)d_in[20];

    const size_t SD = (size_t)SEQ * DMODEL;       // 2M floats
    float* x   = (float*)d_ws;
    float* hb  = x   + SD;
    float* qb  = hb  + SD;
    float* kb  = qb  + SD;
    float* vb  = kb  + SD;
    float* ob  = vb  + SD;
    float* mid = ob  + SD;                        // 8M floats

    const size_t DD  = (size_t)DMODEL * DMODEL;
    const size_t DD4 = (size_t)DMODEL * 4 * DMODEL;

    embed_kernel<<<SEQ, 256, 0, stream>>>(ids, emb, pos, x);

    for (int l = 0; l < NLAYER; ++l) {
        ln_kernel<<<SEQ, 256, 0, stream>>>(x, ln1g + l * DMODEL, ln1b + l * DMODEL, hb);

        gemm_kernel<false, 0><<<dim3(16, 8), 256, 0, stream>>>(
            hb, wq + l * DD, bq + l * DMODEL, nullptr, qb, SEQ, DMODEL, DMODEL);
        gemm_kernel<false, 0><<<dim3(16, 8), 256, 0, stream>>>(
            hb, wk + l * DD, bk + l * DMODEL, nullptr, kb, SEQ, DMODEL, DMODEL);
        gemm_kernel<false, 0><<<dim3(16, 8), 256, 0, stream>>>(
            hb, wv + l * DD, bv + l * DMODEL, nullptr, vb, SEQ, DMODEL, DMODEL);

        attn_kernel<<<dim3(SEQ / 64, NHEAD), 256, 0, stream>>>(qb, kb, vb, ob);

        gemm_kernel<false, 0><<<dim3(16, 8), 256, 0, stream>>>(
            ob, wo + l * DD, bo + l * DMODEL, x, x, SEQ, DMODEL, DMODEL);

        ln_kernel<<<SEQ, 256, 0, stream>>>(x, ln2g + l * DMODEL, ln2b + l * DMODEL, hb);

        gemm_kernel<false, 1><<<dim3(16, 32), 256, 0, stream>>>(
            hb, w1 + l * DD4, b1 + l * 4 * DMODEL, nullptr, mid, SEQ, 4 * DMODEL, DMODEL);

        gemm_kernel<false, 0><<<dim3(16, 8), 256, 0, stream>>>(
            mid, w2 + l * DD4, b2 + l * DMODEL, x, x, SEQ, DMODEL, 4 * DMODEL);
    }

    ln_kernel<<<SEQ, 256, 0, stream>>>(x, outg, outb, hb);

    // logits = x @ emb.T  (emb is [V, D] = [N, K] row-major -> BT path)
    gemm_kernel<true, 0><<<dim3(16, VOCAB / 128), 256, 0, stream>>>(
        hb, emb, nullptr, nullptr, (float*)d_out, SEQ, VOCAB, DMODEL);
}

// Round 2
// 1659.085 us; speedup vs baseline: 1.3252x; 1.3252x over previous
//
#include <hip/hip_runtime.h>
#include <hip/hip_bf16.h>
#include <math.h>

// Model constants: V=32000, D=1024, H=16, L=2, S=2048, W=256
#define SEQ    2048
#define DMODEL 1024
#define NHEAD  16
#define HDIM   64
#define NLAYER 2
#define VOCAB  32000
#define HALFW  128   // W//2

typedef float  f32x4  __attribute__((ext_vector_type(4)));
typedef short  s16x8  __attribute__((ext_vector_type(8)));

// ---------- helpers ----------
__device__ __forceinline__ unsigned bf16_rne(float x) {
    unsigned b = __builtin_bit_cast(unsigned, x);
    return (b + 0x7FFFu + ((b >> 16) & 1u)) >> 16;
}
__device__ __forceinline__ unsigned pack2(float lo, float hi) {
    return bf16_rne(lo) | (bf16_rne(hi) << 16);
}
__device__ __forceinline__ void gl_lds16(const void* g, void* l) {
    __builtin_amdgcn_global_load_lds(
        (const __attribute__((address_space(1))) unsigned*)g,
        (__attribute__((address_space(3))) unsigned*)l, 16, 0, 0);
}

// ---------- embedding ----------
__global__ __launch_bounds__(256) void embed_kernel(
    const int* __restrict__ ids, const float* __restrict__ emb,
    const float* __restrict__ pos, float* __restrict__ X)
{
    const int s = blockIdx.x;
    const int t = threadIdx.x;
    const int id = ids[s];
    f32x4 e = *(const f32x4*)(emb + (size_t)id * DMODEL + t * 4);
    f32x4 p = *(const f32x4*)(pos + (size_t)s  * DMODEL + t * 4);
    *(f32x4*)(X + (size_t)s * DMODEL + t * 4) = e + p;
}

// ---------- f32 -> bf16 elementwise (8 elems/thread) ----------
__global__ __launch_bounds__(256) void convert_bf16_kernel(
    const float* __restrict__ X, unsigned short* __restrict__ Y)
{
    const size_t i = (size_t)blockIdx.x * 256 + threadIdx.x;
    f32x4 a = *(const f32x4*)(X + i * 8);
    f32x4 b = *(const f32x4*)(X + i * 8 + 4);
    uint4 u = make_uint4(pack2(a.x, a.y), pack2(a.z, a.w),
                         pack2(b.x, b.y), pack2(b.z, b.w));
    *(uint4*)(Y + i * 8) = u;
}

// ---------- W[K,N] f32 -> Wt[N,K] bf16, 64x64 tiles ----------
__global__ __launch_bounds__(256) void transpose_bf16_kernel(
    const float* __restrict__ W, unsigned short* __restrict__ Wt, int K, int N)
{
    __shared__ unsigned short tile[64][65];
    const int k0 = blockIdx.x * 64;
    const int n0 = blockIdx.y * 64;
    const int t = threadIdx.x;
    const int tr = t >> 6;     // 0..3
    const int tc = t & 63;
    #pragma unroll
    for (int i = 0; i < 16; ++i) {
        int r = i * 4 + tr;
        tile[r][tc] = (unsigned short)bf16_rne(W[(size_t)(k0 + r) * N + n0 + tc]);
    }
    __syncthreads();
    #pragma unroll
    for (int i = 0; i < 16; ++i) {
        int r = i * 4 + tr;
        Wt[(size_t)(n0 + r) * K + k0 + tc] = tile[tc][r];
    }
}

// ---------- pack 3 bias vectors [D] into [3D] ----------
__global__ __launch_bounds__(256) void pack3_kernel(
    const float* __restrict__ a, const float* __restrict__ b,
    const float* __restrict__ c, float* __restrict__ out)
{
    const int i = blockIdx.x * 256 + threadIdx.x;   // 0..3071
    float v = (i < 1024) ? a[i] : (i < 2048 ? b[i - 1024] : c[i - 2048]);
    out[i] = v;
}

// ---------- layernorm, bf16 output ----------
__global__ __launch_bounds__(256) void ln_bf16_kernel(
    const float* __restrict__ X, const float* __restrict__ G,
    const float* __restrict__ Bb, unsigned short* __restrict__ Y)
{
    const int row = blockIdx.x;
    const int t = threadIdx.x;
    const float* xp = X + (size_t)row * DMODEL;
    f32x4 v = *(const f32x4*)(xp + t * 4);
    float s1 = v.x + v.y + v.z + v.w;
    float s2 = v.x * v.x + v.y * v.y + v.z * v.z + v.w * v.w;
    #pragma unroll
    for (int off = 32; off; off >>= 1) {
        s1 += __shfl_down(s1, off);
        s2 += __shfl_down(s2, off);
    }
    __shared__ float red[8];
    const int wave = t >> 6, lane = t & 63;
    if (lane == 0) { red[wave] = s1; red[wave + 4] = s2; }
    __syncthreads();
    s1 = red[0] + red[1] + red[2] + red[3];
    s2 = red[4] + red[5] + red[6] + red[7];
    const float mu  = s1 * (1.0f / DMODEL);
    const float var = s2 * (1.0f / DMODEL) - mu * mu;
    const float rs  = rsqrtf(var + 1e-5f);
    f32x4 g = *(const f32x4*)(G + t * 4);
    f32x4 b = *(const f32x4*)(Bb + t * 4);
    float y0 = (v.x - mu) * rs * g.x + b.x;
    float y1 = (v.y - mu) * rs * g.y + b.y;
    float y2 = (v.z - mu) * rs * g.z + b.z;
    float y3 = (v.w - mu) * rs * g.w + b.w;
    *(uint2*)(Y + (size_t)row * DMODEL + t * 4) = make_uint2(pack2(y0, y1), pack2(y2, y3));
}

// ---------- GEMM: C[M,N] = A[M,K](bf16) * Bt[N,K](bf16) ----------
// BN=128, BK=32. BM in {64,128}. 256 threads = 4 waves.
// Staging via global_load_lds width=16 (m97 structure): zero VALU, LDS rows
// of 64B in exact lane order (wave-uniform base + lane*16 -> row r*16+l/4,
// kofs (l&3)*8).
template<int BM, int GELU, int OUT_BF16>
__global__ __launch_bounds__(256) void gemm_bf16(
    const unsigned short* __restrict__ A,
    const unsigned short* __restrict__ Bt,
    const float* __restrict__ bias, const float* __restrict__ resid,
    float* __restrict__ C, unsigned short* __restrict__ Cb,
    int M, int N, int K)
{
    constexpr int MW = BM / 64;      // waves along M
    constexpr int NW = 4 / MW;       // waves along N
    constexpr int WN = 128 / NW;     // wave tile N
    constexpr int MI = 4;            // wave tile M = 64 -> 4 frags
    constexpr int NI = WN / 16;

    __shared__ unsigned short As[BM * 32];
    __shared__ unsigned short Bs[128 * 32];

    const int t = threadIdx.x;
    const int wave = t >> 6, lane = t & 63;
    const int m0 = blockIdx.x * BM;
    const int n0 = blockIdx.y * 128;
    const int wm = (wave % MW) * 64;
    const int wn = (wave / MW) * WN;
    const int lrow = lane & 15, quad = lane >> 4;

    const int ldsub = lane >> 2;          // row within 16-row chunk
    const int kofs  = (lane & 3) * 8;     // bf16 k-offset

    f32x4 acc[MI][NI] = {};

    const unsigned short* Ap = A + (size_t)m0 * K + kofs;
    const unsigned short* Bp = Bt + (size_t)n0 * K + kofs;

    for (int k0 = 0; k0 < K; k0 += 32) {
        __syncthreads();   // all waves done reading LDS from prev iter
        #pragma unroll
        for (int i = 0; i < MW; ++i) {
            const int r = i * 4 + wave;                 // chunk 0..BM/16-1
            gl_lds16(Ap + (size_t)(r * 16 + ldsub) * K + k0, (char*)As + r * 1024);
        }
        #pragma unroll
        for (int i = 0; i < 2; ++i) {
            const int r = i * 4 + wave;                 // chunk 0..7
            gl_lds16(Bp + (size_t)(r * 16 + ldsub) * K + k0, (char*)Bs + r * 1024);
        }
        __syncthreads();   // drains vmcnt(0): LDS tiles ready

        s16x8 af[MI], bfr[NI];
        #pragma unroll
        for (int i = 0; i < MI; ++i)
            af[i] = *(const s16x8*)(As + (wm + i * 16 + lrow) * 32 + quad * 8);
        #pragma unroll
        for (int j = 0; j < NI; ++j)
            bfr[j] = *(const s16x8*)(Bs + (wn + j * 16 + lrow) * 32 + quad * 8);
        #pragma unroll
        for (int i = 0; i < MI; ++i)
            #pragma unroll
            for (int j = 0; j < NI; ++j)
                acc[i][j] = __builtin_amdgcn_mfma_f32_16x16x32_bf16(af[i], bfr[j], acc[i][j], 0, 0, 0);
    }

    // epilogue: C/D layout col=lane&15, row=quad*4+reg (m89-verified)
    #pragma unroll
    for (int j = 0; j < NI; ++j) {
        const int col = n0 + wn + j * 16 + lrow;
        const float bv = bias ? bias[col] : 0.0f;
        #pragma unroll
        for (int i = 0; i < MI; ++i) {
            #pragma unroll
            for (int r = 0; r < 4; ++r) {
                const int row = m0 + wm + i * 16 + quad * 4 + r;
                float vv = acc[i][j][r] + bv;
                if (GELU) vv = 0.5f * vv * (1.0f + erff(vv * 0.70710678118f));
                const size_t off = (size_t)row * N + col;
                if (OUT_BF16) {
                    Cb[off] = (unsigned short)bf16_rne(vv);
                } else {
                    if (resid) vv += resid[off];
                    C[off] = vv;
                }
            }
        }
    }
}

// ---------- local attention (band |q-k| <= 128), online softmax ----------
// qkv packed [S, 3D] f32; output bf16 [S, D].
__global__ __launch_bounds__(256) void attn_kernel(
    const float* __restrict__ QKV, unsigned short* __restrict__ O)
{
    const int t = threadIdx.x;
    const int h = blockIdx.y;
    const int ql = t >> 2;
    const int chunk = t & 3;
    const int q_abs = blockIdx.x * 64 + ql;
    const float scale = 0.125f;  // 1/sqrt(64)

    const float* qp = QKV + (size_t)q_abs * (3 * DMODEL) + h * HDIM + chunk * 16;
    float qr[16];
    *(f32x4*)(qr + 0)  = *(const f32x4*)(qp + 0);
    *(f32x4*)(qr + 4)  = *(const f32x4*)(qp + 4);
    *(f32x4*)(qr + 8)  = *(const f32x4*)(qp + 8);
    *(f32x4*)(qr + 12) = *(const f32x4*)(qp + 12);

    float m = -1e30f, l = 0.0f;
    float oa[16] = {};

    const int kbase = blockIdx.x * 64 - HALFW;
    for (int j = 0; j < 64 + 2 * HALFW; ++j) {
        const int key = kbase + j;
        const bool valid = (key >= 0) && (key < SEQ) && (abs(key - q_abs) <= HALFW);
        const int kc = min(max(key, 0), SEQ - 1);

        const float* kp = QKV + (size_t)kc * (3 * DMODEL) + DMODEL + h * HDIM + chunk * 16;
        float kr[16];
        *(f32x4*)(kr + 0)  = *(const f32x4*)(kp + 0);
        *(f32x4*)(kr + 4)  = *(const f32x4*)(kp + 4);
        *(f32x4*)(kr + 8)  = *(const f32x4*)(kp + 8);
        *(f32x4*)(kr + 12) = *(const f32x4*)(kp + 12);

        float s = 0.0f;
        #pragma unroll
        for (int i = 0; i < 16; ++i) s += qr[i] * kr[i];
        s += __shfl_xor(s, 1);
        s += __shfl_xor(s, 2);
        s = valid ? s * scale : -1e30f;

        const float mn = fmaxf(m, s);
        const float alpha = __expf(m - mn);
        const float p = valid ? __expf(s - mn) : 0.0f;

        const float* vp = QKV + (size_t)kc * (3 * DMODEL) + 2 * DMODEL + h * HDIM + chunk * 16;
        float vr[16];
        *(f32x4*)(vr + 0)  = *(const f32x4*)(vp + 0);
        *(f32x4*)(vr + 4)  = *(const f32x4*)(vp + 4);
        *(f32x4*)(vr + 8)  = *(const f32x4*)(vp + 8);
        *(f32x4*)(vr + 12) = *(const f32x4*)(vp + 12);

        #pragma unroll
        for (int i = 0; i < 16; ++i) oa[i] = oa[i] * alpha + p * vr[i];
        l = l * alpha + p;
        m = mn;
    }

    const float inv = 1.0f / l;
    unsigned short* op = O + (size_t)q_abs * DMODEL + h * HDIM + chunk * 16;
    uint4 u0 = make_uint4(pack2(oa[0] * inv, oa[1] * inv),  pack2(oa[2] * inv, oa[3] * inv),
                          pack2(oa[4] * inv, oa[5] * inv),  pack2(oa[6] * inv, oa[7] * inv));
    uint4 u1 = make_uint4(pack2(oa[8] * inv, oa[9] * inv),  pack2(oa[10] * inv, oa[11] * inv),
                          pack2(oa[12] * inv, oa[13] * inv), pack2(oa[14] * inv, oa[15] * inv));
    *(uint4*)op = u0;
    *(uint4*)(op + 8) = u1;
}

// ---------- launch ----------
extern "C" void kernel_launch(void* const* d_in, const int* in_sizes, int n_in,
                              void* d_out, int out_size, void* d_ws, size_t ws_size,
                              hipStream_t stream)
{
    const int*   ids  = (const int*)d_in[0];
    const float* emb  = (const float*)d_in[1];
    const float* pos  = (const float*)d_in[2];
    const float* wq   = (const float*)d_in[3];
    const float* bq   = (const float*)d_in[4];
    const float* wk   = (const float*)d_in[5];
    const float* bk   = (const float*)d_in[6];
    const float* wv   = (const float*)d_in[7];
    const float* bv   = (const float*)d_in[8];
    const float* wo   = (const float*)d_in[9];
    const float* bo   = (const float*)d_in[10];
    const float* w1   = (const float*)d_in[11];
    const float* b1   = (const float*)d_in[12];
    const float* w2   = (const float*)d_in[13];
    const float* b2   = (const float*)d_in[14];
    const float* ln1g = (const float*)d_in[15];
    const float* ln1b = (const float*)d_in[16];
    const float* ln2g = (const float*)d_in[17];
    const float* ln2b = (const float*)d_in[18];
    const float* outg = (const float*)d_in[19];
    const float* outb = (const float*)d_in[20];

    const size_t SD = (size_t)SEQ * DMODEL;       // 2M
    char* ws = (char*)d_ws;
    float*          x     = (float*)ws;           ws += SD * 4;                      // 8 MB
    float*          qkv   = (float*)ws;           ws += (size_t)SEQ * 3 * DMODEL * 4; // 25 MB
    unsigned short* hb    = (unsigned short*)ws;  ws += SD * 2;                      // 4 MB
    unsigned short* ob    = (unsigned short*)ws;  ws += SD * 2;                      // 4 MB
    unsigned short* mid   = (unsigned short*)ws;  ws += (size_t)SEQ * 4 * DMODEL * 2; // 16.8 MB
    unsigned short* embT  = (unsigned short*)ws;  ws += (size_t)VOCAB * DMODEL * 2;  // 65.5 MB
    unsigned short* wT    = (unsigned short*)ws;  ws += (size_t)4 * DMODEL * DMODEL * 2; // 8.4 MB
    float*          bias3 = (float*)ws;           ws += 3 * DMODEL * 4;

    const size_t DD  = (size_t)DMODEL * DMODEL;
    const size_t DD4 = (size_t)DMODEL * 4 * DMODEL;

    // emb f32 -> bf16 (layout [V,K] is already the BT layout for logits)
    convert_bf16_kernel<<<(VOCAB * DMODEL) / (256 * 8), 256, 0, stream>>>(emb, embT);

    embed_kernel<<<SEQ, 256, 0, stream>>>(ids, emb, pos, x);

    for (int l = 0; l < NLAYER; ++l) {
        ln_bf16_kernel<<<SEQ, 256, 0, stream>>>(x, ln1g + l * DMODEL, ln1b + l * DMODEL, hb);

        // QKV fused: Wt = [wq^T ; wk^T ; wv^T]  (3072 x 1024)
        transpose_bf16_kernel<<<dim3(16, 16), 256, 0, stream>>>(wq + l * DD, wT,                 DMODEL, DMODEL);
        transpose_bf16_kernel<<<dim3(16, 16), 256, 0, stream>>>(wk + l * DD, wT + DD,            DMODEL, DMODEL);
        transpose_bf16_kernel<<<dim3(16, 16), 256, 0, stream>>>(wv + l * DD, wT + 2 * DD,        DMODEL, DMODEL);
        pack3_kernel<<<12, 256, 0, stream>>>(bq + l * DMODEL, bk + l * DMODEL, bv + l * DMODEL, bias3);

        gemm_bf16<128, 0, 0><<<dim3(16, 24), 256, 0, stream>>>(
            hb, wT, bias3, nullptr, qkv, nullptr, SEQ, 3 * DMODEL, DMODEL);

        attn_kernel<<<dim3(SEQ / 64, NHEAD), 256, 0, stream>>>(qkv, ob);

        transpose_bf16_kernel<<<dim3(16, 16), 256, 0, stream>>>(wo + l * DD, wT, DMODEL, DMODEL);
        gemm_bf16<64, 0, 0><<<dim3(32, 8), 256, 0, stream>>>(
            ob, wT, bo + l * DMODEL, x, x, nullptr, SEQ, DMODEL, DMODEL);

        ln_bf16_kernel<<<SEQ, 256, 0, stream>>>(x, ln2g + l * DMODEL, ln2b + l * DMODEL, hb);

        transpose_bf16_kernel<<<dim3(16, 64), 256, 0, stream>>>(w1 + l * DD4, wT, DMODEL, 4 * DMODEL);
        gemm_bf16<128, 1, 1><<<dim3(16, 32), 256, 0, stream>>>(
            hb, wT, b1 + l * 4 * DMODEL, nullptr, nullptr, mid, SEQ, 4 * DMODEL, DMODEL);

        transpose_bf16_kernel<<<dim3(64, 16), 256, 0, stream>>>(w2 + l * DD4, wT, 4 * DMODEL, DMODEL);
        gemm_bf16<64, 0, 0><<<dim3(32, 8), 256, 0, stream>>>(
            mid, wT, b2 + l * DMODEL, x, x, nullptr, SEQ, DMODEL, 4 * DMODEL);
    }

    ln_bf16_kernel<<<SEQ, 256, 0, stream>>>(x, outg, outb, hb);

    // logits = hb @ embT^T  -> d_out f32
    gemm_bf16<128, 0, 0><<<dim3(16, VOCAB / 128), 256, 0, stream>>>(
        hb, embT, nullptr, nullptr, (float*)d_out, nullptr, SEQ, VOCAB, DMODEL);
}